// Round 1
// baseline (301.064 us; speedup 1.0000x reference)
//
#include <hip/hip_runtime.h>
#include <hip/hip_bf16.h>
#include <cstdint>

typedef unsigned short u16;
typedef unsigned long long u64;
using f32x4 = __attribute__((ext_vector_type(4))) float;
using s16x8 = __attribute__((ext_vector_type(8))) short;

#define NB 2
#define NT 2048
#define NC 1024
#define NH 16
#define HD 64

__device__ __forceinline__ u16 f2b(float f) {
    unsigned u = __float_as_uint(f);
    unsigned r = (u + 0x7FFFu + ((u >> 16) & 1u)) >> 16;
    return (u16)r;
}

__device__ __forceinline__ void gl_lds16(const void* g, const void* l) {
    __builtin_amdgcn_global_load_lds(
        (const __attribute__((address_space(1))) unsigned int*)g,
        (__attribute__((address_space(3))) unsigned int*)l, 16, 0, 0);
}

// ---------------- conversion: f32 -> bf16, 4 elems/thread ----------------
__global__ __launch_bounds__(256) void conv_bf16(const float* __restrict__ in,
                                                 u16* __restrict__ out, int n4) {
    int i = blockIdx.x * 256 + threadIdx.x;
    if (i >= n4) return;
    float4 v = ((const float4*)in)[i];
    u64 pack = (u64)f2b(v.x) | ((u64)f2b(v.y) << 16) |
               ((u64)f2b(v.z) << 32) | ((u64)f2b(v.w) << 48);
    ((u64*)out)[i] = pack;
}

// ------------- transpose+convert: W[K][N] f32 -> Wt[N][K] bf16 -----------
__global__ __launch_bounds__(256) void transpose_bf16(const float* __restrict__ W,
                                                      u16* __restrict__ Wt,
                                                      int K, int N) {
    __shared__ u16 s[64][65];
    const int n0 = blockIdx.x * 64, k0 = blockIdx.y * 64;
    const int t = threadIdx.x;
    const int tr = t >> 4, tc4 = (t & 15) * 4;
#pragma unroll
    for (int i = 0; i < 4; i++) {
        int r = tr + i * 16;
        float4 v = *(const float4*)&W[(size_t)(k0 + r) * N + n0 + tc4];
        s[r][tc4 + 0] = f2b(v.x);
        s[r][tc4 + 1] = f2b(v.y);
        s[r][tc4 + 2] = f2b(v.z);
        s[r][tc4 + 3] = f2b(v.w);
    }
    __syncthreads();
#pragma unroll
    for (int i = 0; i < 4; i++) {
        int nl = tr + i * 16;
        u64 pack = (u64)s[tc4 + 0][nl] | ((u64)s[tc4 + 1][nl] << 16) |
                   ((u64)s[tc4 + 2][nl] << 32) | ((u64)s[tc4 + 3][nl] << 48);
        *(u64*)&Wt[(size_t)(n0 + nl) * K + k0 + tc4] = pack;
    }
}

// --------- GEMM: A[M][K]bf16 * Bt[N][K]bf16 + bias -> C[M][N] ------------
// 128x128 tile, BK=32, 4 waves (2x2), each wave 64x64 via 4x4 16x16x32 MFMA.
template <int OUT_BF16>
__global__ __launch_bounds__(256) void gemm_bt(const u16* __restrict__ A,
                                               const u16* __restrict__ Bt,
                                               const float* __restrict__ bias,
                                               void* __restrict__ Cout,
                                               int M, int N, int K) {
    __shared__ u16 As[128 * 32];
    __shared__ u16 Bs[128 * 32];
    const int tid = threadIdx.x;
    const int lane = tid & 63, w = tid >> 6;
    const int m0 = blockIdx.y * 128, n0 = blockIdx.x * 128;
    const int wm = w >> 1, wn = w & 1;
    f32x4 acc[4][4] = {};

    const int srow = 32 * w + (lane >> 2);   // staging row within tile (+16 for 2nd)
    const int scol = (lane & 3) * 8;

    for (int k0 = 0; k0 < K; k0 += 32) {
        gl_lds16(&A[(size_t)(m0 + srow) * K + k0 + scol], &As[w * 1024 + lane * 8]);
        gl_lds16(&A[(size_t)(m0 + srow + 16) * K + k0 + scol], &As[w * 1024 + 512 + lane * 8]);
        gl_lds16(&Bt[(size_t)(n0 + srow) * K + k0 + scol], &Bs[w * 1024 + lane * 8]);
        gl_lds16(&Bt[(size_t)(n0 + srow + 16) * K + k0 + scol], &Bs[w * 1024 + 512 + lane * 8]);
        __syncthreads();

        s16x8 af[4], bf[4];
#pragma unroll
        for (int mt = 0; mt < 4; mt++)
            af[mt] = *(const s16x8*)&As[(wm * 64 + mt * 16 + (lane & 15)) * 32 + (lane >> 4) * 8];
#pragma unroll
        for (int nt = 0; nt < 4; nt++)
            bf[nt] = *(const s16x8*)&Bs[(wn * 64 + nt * 16 + (lane & 15)) * 32 + (lane >> 4) * 8];
#pragma unroll
        for (int mt = 0; mt < 4; mt++)
#pragma unroll
            for (int nt = 0; nt < 4; nt++)
                acc[mt][nt] = __builtin_amdgcn_mfma_f32_16x16x32_bf16(af[mt], bf[nt], acc[mt][nt], 0, 0, 0);
        __syncthreads();
    }

#pragma unroll
    for (int mt = 0; mt < 4; mt++) {
        int row = m0 + wm * 64 + mt * 16 + (lane >> 4) * 4;
#pragma unroll
        for (int nt = 0; nt < 4; nt++) {
            int col = n0 + wn * 64 + nt * 16 + (lane & 15);
            float bs = bias[col];
#pragma unroll
            for (int r = 0; r < 4; r++) {
                float v = acc[mt][nt][r] + bs;
                if (OUT_BF16)
                    ((u16*)Cout)[(size_t)(row + r) * N + col] = f2b(v);
                else
                    ((float*)Cout)[(size_t)(row + r) * N + col] = v;
            }
        }
    }
}

// ---------------- causal flash attention ---------------------------------
// qkv [B*T][3C] bf16 (q|k|v blocks of C each, head h at h*64 within block).
// Block: 64 q-rows (4 waves x 16), one (b,h). KV tiles of 32.
__global__ __launch_bounds__(256) void attn_kernel(const u16* __restrict__ qkv,
                                                   u16* __restrict__ y) {
    __shared__ u16 Klds[32 * 64];      // [32 kv][64 d] linear (global_load_lds)
    __shared__ u16 Vt[64 * 48];        // [64 d][32 kv] +pad
    __shared__ u16 Pl[4][16 * 48];     // per-wave P [16 q][32 kv] +pad

    const int tid = threadIdx.x, lane = tid & 63, w = tid >> 6;
    const int qb = blockIdx.x * 64;
    const int b = blockIdx.y >> 4, h = blockIdx.y & 15;
    const size_t rowbase = (size_t)b * NT * (3 * NC);
    const int qw = qb + w * 16;

    // Q fragments (row = lane&15, k-chunk = (lane>>4)*8)
    const u16* qptr = qkv + rowbase + (size_t)(qw + (lane & 15)) * (3 * NC) + h * HD;
    const s16x8 aq0 = *(const s16x8*)(qptr + (lane >> 4) * 8);
    const s16x8 aq1 = *(const s16x8*)(qptr + 32 + (lane >> 4) * 8);

    f32x4 accy[4] = {};
    float mrow[4], lrow[4];
#pragma unroll
    for (int r = 0; r < 4; r++) { mrow[r] = -INFINITY; lrow[r] = 0.f; }

    const float scale = 0.125f;  // 1/sqrt(64)
    const int kv_end = qb + 64;  // uniform across block (extra tiles fully masked per-wave)

    for (int kv0 = 0; kv0 < kv_end; kv0 += 32) {
        __syncthreads();  // protect Klds/Vt/Pl overwrite (prev iter reads done)

        // stage K tile [32][64] linear: wave w -> 1KB chunk w
        gl_lds16(qkv + rowbase + (size_t)(kv0 + w * 8 + (lane >> 3)) * (3 * NC) + NC + h * HD + (lane & 7) * 8,
                 &Klds[w * 512 + lane * 8]);
        // stage V transposed: Vt[d][kv]
        {
            int kvl = tid >> 3, c8 = (tid & 7) * 8;
            s16x8 vv = *(const s16x8*)(qkv + rowbase + (size_t)(kv0 + kvl) * (3 * NC) + 2 * NC + h * HD + c8);
#pragma unroll
            for (int j = 0; j < 8; j++) Vt[(c8 + j) * 48 + kvl] = (u16)vv[j];
        }
        __syncthreads();

        // S = Q K^T : two 16x16 tiles (kv 0..15, 16..31)
        f32x4 s0 = {0.f, 0.f, 0.f, 0.f}, s1 = {0.f, 0.f, 0.f, 0.f};
        {
            s16x8 bk;
            bk = *(const s16x8*)&Klds[(lane & 15) * 64 + (lane >> 4) * 8];
            s0 = __builtin_amdgcn_mfma_f32_16x16x32_bf16(aq0, bk, s0, 0, 0, 0);
            bk = *(const s16x8*)&Klds[(lane & 15) * 64 + 32 + (lane >> 4) * 8];
            s0 = __builtin_amdgcn_mfma_f32_16x16x32_bf16(aq1, bk, s0, 0, 0, 0);
            bk = *(const s16x8*)&Klds[(16 + (lane & 15)) * 64 + (lane >> 4) * 8];
            s1 = __builtin_amdgcn_mfma_f32_16x16x32_bf16(aq0, bk, s1, 0, 0, 0);
            bk = *(const s16x8*)&Klds[(16 + (lane & 15)) * 64 + 32 + (lane >> 4) * 8];
            s1 = __builtin_amdgcn_mfma_f32_16x16x32_bf16(aq1, bk, s1, 0, 0, 0);
        }

        // mask + scale; C-layout: col = lane&15, row q = qw + (lane>>4)*4 + r
        const int col0 = kv0 + (lane & 15), col1 = col0 + 16;
        float sv0[4], sv1[4], pmax[4];
#pragma unroll
        for (int r = 0; r < 4; r++) {
            int qg = qw + (lane >> 4) * 4 + r;
            sv0[r] = (col0 <= qg) ? s0[r] * scale : -1e30f;
            sv1[r] = (col1 <= qg) ? s1[r] * scale : -1e30f;
            pmax[r] = fmaxf(sv0[r], sv1[r]);
        }
#pragma unroll
        for (int off = 1; off < 16; off <<= 1)
#pragma unroll
            for (int r = 0; r < 4; r++)
                pmax[r] = fmaxf(pmax[r], __shfl_xor(pmax[r], off));

        float p0[4], p1[4], psum[4];
#pragma unroll
        for (int r = 0; r < 4; r++) {
            float mnew = fmaxf(mrow[r], pmax[r]);
            float alpha = __expf(mrow[r] - mnew);  // exp(-inf)=0 first tile
            mrow[r] = mnew;
            p0[r] = __expf(sv0[r] - mnew);
            p1[r] = __expf(sv1[r] - mnew);
            psum[r] = p0[r] + p1[r];
            lrow[r] *= alpha;
#pragma unroll
            for (int db = 0; db < 4; db++) accy[db][r] *= alpha;
        }
#pragma unroll
        for (int off = 1; off < 16; off <<= 1)
#pragma unroll
            for (int r = 0; r < 4; r++)
                psum[r] += __shfl_xor(psum[r], off);
#pragma unroll
        for (int r = 0; r < 4; r++) lrow[r] += psum[r];

        // write P (bf16) to per-wave LDS [q][kv]
        u16* Pw = &Pl[w][0];
#pragma unroll
        for (int r = 0; r < 4; r++) {
            int q = (lane >> 4) * 4 + r;
            Pw[q * 48 + (lane & 15)] = f2b(p0[r]);
            Pw[q * 48 + 16 + (lane & 15)] = f2b(p1[r]);
        }
        __syncthreads();

        // PV: A = P[16q][32kv], B = V[32kv][64d] (from Vt)
        s16x8 pf = *(const s16x8*)&Pw[(lane & 15) * 48 + (lane >> 4) * 8];
#pragma unroll
        for (int db = 0; db < 4; db++) {
            s16x8 vf = *(const s16x8*)&Vt[(db * 16 + (lane & 15)) * 48 + (lane >> 4) * 8];
            accy[db] = __builtin_amdgcn_mfma_f32_16x16x32_bf16(pf, vf, accy[db], 0, 0, 0);
        }
    }

    // epilogue: y[b*T+q][h*64 + d] = accy / l
#pragma unroll
    for (int r = 0; r < 4; r++) {
        int qg = qw + (lane >> 4) * 4 + r;
        float inv = 1.f / lrow[r];
        size_t base = (size_t)(b * NT + qg) * NC + h * HD;
#pragma unroll
        for (int db = 0; db < 4; db++)
            y[base + db * 16 + (lane & 15)] = f2b(accy[db][r] * inv);
    }
}

extern "C" void kernel_launch(void* const* d_in, const int* in_sizes, int n_in,
                              void* d_out, int out_size, void* d_ws, size_t ws_size,
                              hipStream_t stream) {
    const float* x  = (const float*)d_in[0];
    // d_in[1] = mask (causal tril) — computed analytically, not read
    const float* Wa = (const float*)d_in[2];
    const float* ba = (const float*)d_in[3];
    const float* Wp = (const float*)d_in[4];
    const float* bp = (const float*)d_in[5];
    float* out = (float*)d_out;

    char* ws = (char*)d_ws;
    u16* xb  = (u16*)(ws);                       // 8 MiB  [4096][1024]
    u16* WaT = (u16*)(ws + (8ull << 20));        // 6 MiB  [3072][1024]
    u16* WpT = (u16*)(ws + (14ull << 20));       // 2 MiB  [1024][1024]
    u16* qkv = (u16*)(ws + (16ull << 20));       // 24 MiB [4096][3072]
    u16* yb  = (u16*)(ws + (40ull << 20));       // 8 MiB  [4096][1024]
    // total 48 MiB of d_ws

    const int M = NB * NT;  // 4096

    conv_bf16<<<(M * NC / 4 + 255) / 256, 256, 0, stream>>>(x, xb, M * NC / 4);
    transpose_bf16<<<dim3(3 * NC / 64, NC / 64), 256, 0, stream>>>(Wa, WaT, NC, 3 * NC);
    transpose_bf16<<<dim3(NC / 64, NC / 64), 256, 0, stream>>>(Wp, WpT, NC, NC);

    gemm_bt<1><<<dim3(3 * NC / 128, M / 128), 256, 0, stream>>>(xb, WaT, ba, qkv, M, 3 * NC, NC);

    attn_kernel<<<dim3(NT / 64, NB * NH), 256, 0, stream>>>(qkv, yb);

    gemm_bt<0><<<dim3(NC / 128, M / 128), 256, 0, stream>>>(yb, WpT, bp, out, M, NC, NC);
}

// Round 2
// 186.499 us; speedup vs baseline: 1.6143x; 1.6143x over previous
//
#include <hip/hip_runtime.h>
#include <hip/hip_bf16.h>
#include <cstdint>

typedef unsigned short u16;
typedef unsigned int u32;
typedef unsigned long long u64;
using f32x4 = __attribute__((ext_vector_type(4))) float;
using s16x8 = __attribute__((ext_vector_type(8))) short;
using u32x4 = __attribute__((ext_vector_type(4))) u32;

#define NB 2
#define NT 2048
#define NC 1024
#define NH 16
#define HD 64

__device__ __forceinline__ u16 f2b(float f) {
    unsigned u = __float_as_uint(f);
    unsigned r = (u + 0x7FFFu + ((u >> 16) & 1u)) >> 16;
    return (u16)r;
}

__device__ __forceinline__ u32 cvtpk(float a, float b) {
    u32 r;
    asm("v_cvt_pk_bf16_f32 %0, %1, %2" : "=v"(r) : "v"(a), "v"(b));
    return r;
}
__device__ __forceinline__ void swap32(u32& a, u32& b) {
    asm("v_permlane32_swap_b32 %0, %1" : "+v"(a), "+v"(b));
}
__device__ __forceinline__ void swap16(u32& a, u32& b) {
    asm("v_permlane16_swap_b32 %0, %1" : "+v"(a), "+v"(b));
}

__device__ __forceinline__ void gl_lds16(const void* g, const void* l) {
    __builtin_amdgcn_global_load_lds(
        (const __attribute__((address_space(1))) unsigned int*)g,
        (__attribute__((address_space(3))) unsigned int*)l, 16, 0, 0);
}

// ---------------- conversion: f32 -> bf16, 4 elems/thread ----------------
__global__ __launch_bounds__(256) void conv_bf16(const float* __restrict__ in,
                                                 u16* __restrict__ out, int n4) {
    int i = blockIdx.x * 256 + threadIdx.x;
    if (i >= n4) return;
    float4 v = ((const float4*)in)[i];
    u64 pack = (u64)f2b(v.x) | ((u64)f2b(v.y) << 16) |
               ((u64)f2b(v.z) << 32) | ((u64)f2b(v.w) << 48);
    ((u64*)out)[i] = pack;
}

// ------------- transpose+convert: W[K][N] f32 -> Wt[N][K] bf16 -----------
__global__ __launch_bounds__(256) void transpose_bf16(const float* __restrict__ W,
                                                      u16* __restrict__ Wt,
                                                      int K, int N) {
    __shared__ u16 s[64][65];
    const int n0 = blockIdx.x * 64, k0 = blockIdx.y * 64;
    const int t = threadIdx.x;
    const int tr = t >> 4, tc4 = (t & 15) * 4;
#pragma unroll
    for (int i = 0; i < 4; i++) {
        int r = tr + i * 16;
        float4 v = *(const float4*)&W[(size_t)(k0 + r) * N + n0 + tc4];
        s[r][tc4 + 0] = f2b(v.x);
        s[r][tc4 + 1] = f2b(v.y);
        s[r][tc4 + 2] = f2b(v.z);
        s[r][tc4 + 3] = f2b(v.w);
    }
    __syncthreads();
#pragma unroll
    for (int i = 0; i < 4; i++) {
        int nl = tr + i * 16;
        u64 pack = (u64)s[tc4 + 0][nl] | ((u64)s[tc4 + 1][nl] << 16) |
                   ((u64)s[tc4 + 2][nl] << 32) | ((u64)s[tc4 + 3][nl] << 48);
        *(u64*)&Wt[(size_t)(n0 + nl) * K + k0 + tc4] = pack;
    }
}

// --------- GEMM: A[M][K]bf16 * Bt[N][K]bf16 + bias -> C[M][N] ------------
template <int OUT_BF16>
__global__ __launch_bounds__(256) void gemm_bt(const u16* __restrict__ A,
                                               const u16* __restrict__ Bt,
                                               const float* __restrict__ bias,
                                               void* __restrict__ Cout,
                                               int M, int N, int K) {
    __shared__ u16 As[128 * 32];
    __shared__ u16 Bs[128 * 32];
    const int tid = threadIdx.x;
    const int lane = tid & 63, w = tid >> 6;
    const int m0 = blockIdx.y * 128, n0 = blockIdx.x * 128;
    const int wm = w >> 1, wn = w & 1;
    f32x4 acc[4][4] = {};

    const int srow = 32 * w + (lane >> 2);
    const int scol = (lane & 3) * 8;

    for (int k0 = 0; k0 < K; k0 += 32) {
        gl_lds16(&A[(size_t)(m0 + srow) * K + k0 + scol], &As[w * 1024 + lane * 8]);
        gl_lds16(&A[(size_t)(m0 + srow + 16) * K + k0 + scol], &As[w * 1024 + 512 + lane * 8]);
        gl_lds16(&Bt[(size_t)(n0 + srow) * K + k0 + scol], &Bs[w * 1024 + lane * 8]);
        gl_lds16(&Bt[(size_t)(n0 + srow + 16) * K + k0 + scol], &Bs[w * 1024 + 512 + lane * 8]);
        __syncthreads();

        s16x8 af[4], bf[4];
#pragma unroll
        for (int mt = 0; mt < 4; mt++)
            af[mt] = *(const s16x8*)&As[(wm * 64 + mt * 16 + (lane & 15)) * 32 + (lane >> 4) * 8];
#pragma unroll
        for (int nt = 0; nt < 4; nt++)
            bf[nt] = *(const s16x8*)&Bs[(wn * 64 + nt * 16 + (lane & 15)) * 32 + (lane >> 4) * 8];
#pragma unroll
        for (int mt = 0; mt < 4; mt++)
#pragma unroll
            for (int nt = 0; nt < 4; nt++)
                acc[mt][nt] = __builtin_amdgcn_mfma_f32_16x16x32_bf16(af[mt], bf[nt], acc[mt][nt], 0, 0, 0);
        __syncthreads();
    }

#pragma unroll
    for (int mt = 0; mt < 4; mt++) {
        int row = m0 + wm * 64 + mt * 16 + (lane >> 4) * 4;
#pragma unroll
        for (int nt = 0; nt < 4; nt++) {
            int col = n0 + wn * 64 + nt * 16 + (lane & 15);
            float bs = bias[col];
#pragma unroll
            for (int r = 0; r < 4; r++) {
                float v = acc[mt][nt][r] + bs;
                if (OUT_BF16)
                    ((u16*)Cout)[(size_t)(row + r) * N + col] = f2b(v);
                else
                    ((float*)Cout)[(size_t)(row + r) * N + col] = v;
            }
        }
    }
}

// --------- V transpose: qkv v-part [b][t][h*64+d] -> Vt[b*16+h][d][t] ----
__global__ __launch_bounds__(256) void v_transpose(const u16* __restrict__ qkv,
                                                   u16* __restrict__ Vt) {
    __shared__ __align__(16) u16 s[64][72];
    const int t0 = blockIdx.x * 64;
    const int b = blockIdx.y >> 4, h = blockIdx.y & 15;
    const int t = threadIdx.x;
    const int r = t >> 2, c0 = (t & 3) * 16;
    const u16* src = qkv + (size_t)b * NT * (3 * NC) + (size_t)(t0 + r) * (3 * NC) + 2 * NC + h * HD + c0;
    *(s16x8*)&s[r][c0] = *(const s16x8*)src;
    *(s16x8*)&s[r][c0 + 8] = *(const s16x8*)(src + 8);
    __syncthreads();
    u32 arr[8];
#pragma unroll
    for (int jj = 0; jj < 8; jj++)
        arr[jj] = (u32)s[c0 + 2 * jj][r] | ((u32)s[c0 + 2 * jj + 1][r] << 16);
    u16* dst = Vt + ((size_t)(b * NH + h) * HD + r) * NT + t0 + c0;
    u32x4 lo, hi;
    lo[0] = arr[0]; lo[1] = arr[1]; lo[2] = arr[2]; lo[3] = arr[3];
    hi[0] = arr[4]; hi[1] = arr[5]; hi[2] = arr[6]; hi[3] = arr[7];
    *(u32x4*)dst = lo;
    *(u32x4*)(dst + 8) = hi;
}

// ---------------- causal flash attention, 1 wave / 32 q-rows, no LDS -----
__global__ __launch_bounds__(64, 2) void attn_kernel(const u16* __restrict__ qkv,
                                                     const u16* __restrict__ Vt,
                                                     u16* __restrict__ yb) {
    const int l = threadIdx.x & 63;
    const int q16 = l & 15, g = l >> 4;
    // bijective XCD remap: 4 heads per XCD, longest diagonal first
    const int f = blockIdx.x;
    const int xcd = f & 7, idx = f >> 3;
    const int head = xcd * 4 + (idx >> 6);
    const int qc = 63 - (idx & 63);
    const int b = head >> 4, h = head & 15;
    const int qw = qc * 32;

    const u16* qkvb = qkv + (size_t)b * NT * (3 * NC);
    s16x8 qf[2][2];
#pragma unroll
    for (int j = 0; j < 2; j++)
#pragma unroll
        for (int kc = 0; kc < 2; kc++)
            qf[j][kc] = *(const s16x8*)(qkvb + (size_t)(qw + 16 * j + q16) * (3 * NC) + h * HD + kc * 32 + g * 8);

    const u16* kb = qkvb + (size_t)q16 * (3 * NC) + NC + h * HD + g * 8;
    const u16* vtb = Vt + ((size_t)(b * NH + h) * HD + q16) * NT + g * 8;

    f32x4 yacc[4][2] = {};  // [dt][j]: y^T, row d=16dt+4g+r, col q=q16 (+16j)
    float m2[2] = {-INFINITY, -INFINITY};
    float lsum[2] = {0.f, 0.f};
    const float sc2 = 0.125f * 1.44269504088896340736f;  // scale * log2(e)

    for (int kv0 = 0; kv0 <= qw; kv0 += 32) {
        s16x8 kf[2][2], vf[4];
#pragma unroll
        for (int i = 0; i < 2; i++)
#pragma unroll
            for (int kc = 0; kc < 2; kc++)
                kf[i][kc] = *(const s16x8*)(kb + (size_t)(kv0 + 16 * i) * (3 * NC) + kc * 32);
#pragma unroll
        for (int dt = 0; dt < 4; dt++)
            vf[dt] = *(const s16x8*)(vtb + (size_t)(16 * dt) * NT + kv0);

        // S^T = K Q^T : lane holds S[q=16j+q16][kv=kv0+16i+4g+r]
        f32x4 sacc[2][2] = {};
#pragma unroll
        for (int i = 0; i < 2; i++)
#pragma unroll
            for (int kc = 0; kc < 2; kc++)
#pragma unroll
                for (int j = 0; j < 2; j++)
                    sacc[i][j] = __builtin_amdgcn_mfma_f32_16x16x32_bf16(kf[i][kc], qf[j][kc], sacc[i][j], 0, 0, 0);

        if (kv0 == qw) {  // diagonal tile: causal mask
#pragma unroll
            for (int i = 0; i < 2; i++)
#pragma unroll
                for (int j = 0; j < 2; j++)
#pragma unroll
                    for (int r = 0; r < 4; r++)
                        if (16 * i + 4 * g + r > 16 * j + q16) sacc[i][j][r] = -1e30f;
        }

        // row max (raw domain), reduce over lane groups {q16, +16, +32, +48}
        float pm[2];
#pragma unroll
        for (int j = 0; j < 2; j++) {
            float a = fmaxf(fmaxf(sacc[0][j][0], sacc[0][j][1]), fmaxf(sacc[0][j][2], sacc[0][j][3]));
            float c = fmaxf(fmaxf(sacc[1][j][0], sacc[1][j][1]), fmaxf(sacc[1][j][2], sacc[1][j][3]));
            pm[j] = fmaxf(a, c);
            pm[j] = fmaxf(pm[j], __shfl_xor(pm[j], 16));
            pm[j] = fmaxf(pm[j], __shfl_xor(pm[j], 32));
        }
        // defer-max: rescale only when a new max appears anywhere in the wave
        float need = fmaxf(pm[0] * sc2 - m2[0], pm[1] * sc2 - m2[1]);
        if (__any(need > 0.f)) {
#pragma unroll
            for (int j = 0; j < 2; j++) {
                float mn = fmaxf(m2[j], pm[j] * sc2);
                float al = exp2f(m2[j] - mn);
                m2[j] = mn;
                lsum[j] *= al;
#pragma unroll
                for (int dt = 0; dt < 4; dt++)
#pragma unroll
                    for (int r = 0; r < 4; r++) yacc[dt][j][r] *= al;
            }
        }

        float p[2][2][4], ps[2];
#pragma unroll
        for (int j = 0; j < 2; j++) {
            float s0 = 0.f;
#pragma unroll
            for (int i = 0; i < 2; i++)
#pragma unroll
                for (int r = 0; r < 4; r++) {
                    p[i][j][r] = exp2f(fmaf(sacc[i][j][r], sc2, -m2[j]));
                    s0 += p[i][j][r];
                }
            ps[j] = s0;
            ps[j] += __shfl_xor(ps[j], 16);
            ps[j] += __shfl_xor(ps[j], 32);
            lsum[j] += ps[j];
        }

        // pack P to bf16 and build PV B-fragment b[q=q16][kv=8g..8g+7] in-register
        s16x8 pfrag[2];
#pragma unroll
        for (int j = 0; j < 2; j++) {
            u32 C0 = cvtpk(p[0][j][0], p[0][j][1]);
            u32 C1 = cvtpk(p[0][j][2], p[0][j][3]);
            u32 D0 = cvtpk(p[1][j][0], p[1][j][1]);
            u32 D1 = cvtpk(p[1][j][2], p[1][j][3]);
            swap32(C0, D0); swap16(C0, D0);   // C0 -> u32[0], D0 -> u32[2]
            swap32(C1, D1); swap16(C1, D1);   // C1 -> u32[1], D1 -> u32[3]
            u32x4 fr;
            fr[0] = C0; fr[1] = C1; fr[2] = D0; fr[3] = D1;
            pfrag[j] = __builtin_bit_cast(s16x8, fr);
        }

        // y^T += V^T P^T
#pragma unroll
        for (int dt = 0; dt < 4; dt++)
#pragma unroll
            for (int j = 0; j < 2; j++)
                yacc[dt][j] = __builtin_amdgcn_mfma_f32_16x16x32_bf16(vf[dt], pfrag[j], yacc[dt][j], 0, 0, 0);
    }

    // epilogue: yb[b][q][h*64+d] = y / l   (4 bf16 per 8B store)
#pragma unroll
    for (int j = 0; j < 2; j++) {
        float inv = 1.f / lsum[j];
        size_t rowoff = ((size_t)(b * NT + qw + 16 * j + q16)) * NC + h * HD;
#pragma unroll
        for (int dt = 0; dt < 4; dt++) {
            u32 lo = cvtpk(yacc[dt][j][0] * inv, yacc[dt][j][1] * inv);
            u32 hi = cvtpk(yacc[dt][j][2] * inv, yacc[dt][j][3] * inv);
            u64 pk = (u64)lo | ((u64)hi << 32);
            *(u64*)(yb + rowoff + 16 * dt + 4 * g) = pk;
        }
    }
}

extern "C" void kernel_launch(void* const* d_in, const int* in_sizes, int n_in,
                              void* d_out, int out_size, void* d_ws, size_t ws_size,
                              hipStream_t stream) {
    const float* x  = (const float*)d_in[0];
    const float* Wa = (const float*)d_in[2];
    const float* ba = (const float*)d_in[3];
    const float* Wp = (const float*)d_in[4];
    const float* bp = (const float*)d_in[5];
    float* out = (float*)d_out;

    char* ws = (char*)d_ws;
    u16* xb  = (u16*)(ws);                       // 8 MiB  [4096][1024]
    u16* WaT = (u16*)(ws + (8ull << 20));        // 6 MiB  [3072][1024]
    u16* WpT = (u16*)(ws + (14ull << 20));       // 2 MiB  [1024][1024]
    u16* qkv = (u16*)(ws + (16ull << 20));       // 24 MiB [4096][3072]
    u16* yb  = (u16*)(ws + (40ull << 20));       // 8 MiB  [4096][1024]
    u16* Vtb = (u16*)(ws + (48ull << 20));       // 8 MiB  [32][64][2048]

    const int M = NB * NT;  // 4096

    conv_bf16<<<(M * NC / 4 + 255) / 256, 256, 0, stream>>>(x, xb, M * NC / 4);
    transpose_bf16<<<dim3(3 * NC / 64, NC / 64), 256, 0, stream>>>(Wa, WaT, NC, 3 * NC);
    transpose_bf16<<<dim3(NC / 64, NC / 64), 256, 0, stream>>>(Wp, WpT, NC, NC);

    gemm_bt<1><<<dim3(3 * NC / 128, M / 128), 256, 0, stream>>>(xb, WaT, ba, qkv, M, 3 * NC, NC);

    v_transpose<<<dim3(NT / 64, NB * NH), 256, 0, stream>>>(qkv, Vtb);

    attn_kernel<<<dim3(NB * NH * (NT / 32)), 64, 0, stream>>>(qkv, Vtb, yb);

    gemm_bt<0><<<dim3(NC / 128, M / 128), 256, 0, stream>>>(yb, WpT, bp, out, M, NC, NC);
}

// Round 3
// 179.750 us; speedup vs baseline: 1.6749x; 1.0375x over previous
//
#include <hip/hip_runtime.h>
#include <hip/hip_bf16.h>
#include <cstdint>

typedef unsigned short u16;
typedef unsigned int u32;
typedef unsigned long long u64;
using f32x4 = __attribute__((ext_vector_type(4))) float;
using s16x8 = __attribute__((ext_vector_type(8))) short;
using u32x4 = __attribute__((ext_vector_type(4))) u32;

#define NB 2
#define NT 2048
#define NC 1024
#define NH 16
#define HD 64

__device__ __forceinline__ u16 f2b(float f) {
    unsigned u = __float_as_uint(f);
    unsigned r = (u + 0x7FFFu + ((u >> 16) & 1u)) >> 16;
    return (u16)r;
}

__device__ __forceinline__ u32 cvtpk(float a, float b) {
    u32 r;
    asm("v_cvt_pk_bf16_f32 %0, %1, %2" : "=v"(r) : "v"(a), "v"(b));
    return r;
}
__device__ __forceinline__ void swap32(u32& a, u32& b) {
    asm("v_permlane32_swap_b32 %0, %1" : "+v"(a), "+v"(b));
}
__device__ __forceinline__ void swap16(u32& a, u32& b) {
    asm("v_permlane16_swap_b32 %0, %1" : "+v"(a), "+v"(b));
}

__device__ __forceinline__ void gl_lds16(const void* g, const void* l) {
    __builtin_amdgcn_global_load_lds(
        (const __attribute__((address_space(1))) unsigned int*)g,
        (__attribute__((address_space(3))) unsigned int*)l, 16, 0, 0);
}

// ---------------- conversion: f32 -> bf16, 4 elems/thread ----------------
__global__ __launch_bounds__(256) void conv_bf16(const float* __restrict__ in,
                                                 u16* __restrict__ out, int n4) {
    int i = blockIdx.x * 256 + threadIdx.x;
    if (i >= n4) return;
    float4 v = ((const float4*)in)[i];
    u64 pack = (u64)f2b(v.x) | ((u64)f2b(v.y) << 16) |
               ((u64)f2b(v.z) << 32) | ((u64)f2b(v.w) << 48);
    ((u64*)out)[i] = pack;
}

// ------------- transpose+convert: W[K][N] f32 -> Wt[N][K] bf16 -----------
__global__ __launch_bounds__(256) void transpose_bf16(const float* __restrict__ W,
                                                      u16* __restrict__ Wt,
                                                      int K, int N) {
    __shared__ u16 s[64][65];
    const int n0 = blockIdx.x * 64, k0 = blockIdx.y * 64;
    const int t = threadIdx.x;
    const int tr = t >> 4, tc4 = (t & 15) * 4;
#pragma unroll
    for (int i = 0; i < 4; i++) {
        int r = tr + i * 16;
        float4 v = *(const float4*)&W[(size_t)(k0 + r) * N + n0 + tc4];
        s[r][tc4 + 0] = f2b(v.x);
        s[r][tc4 + 1] = f2b(v.y);
        s[r][tc4 + 2] = f2b(v.z);
        s[r][tc4 + 3] = f2b(v.w);
    }
    __syncthreads();
#pragma unroll
    for (int i = 0; i < 4; i++) {
        int nl = tr + i * 16;
        u64 pack = (u64)s[tc4 + 0][nl] | ((u64)s[tc4 + 1][nl] << 16) |
                   ((u64)s[tc4 + 2][nl] << 32) | ((u64)s[tc4 + 3][nl] << 48);
        *(u64*)&Wt[(size_t)(n0 + nl) * K + k0 + tc4] = pack;
    }
}

// --------- GEMM: A[M][K]bf16 * Bt[N][K]bf16 + bias -> C[M][N] ------------
template <int OUT_BF16>
__global__ __launch_bounds__(256) void gemm_bt(const u16* __restrict__ A,
                                               const u16* __restrict__ Bt,
                                               const float* __restrict__ bias,
                                               void* __restrict__ Cout,
                                               int M, int N, int K) {
    __shared__ u16 As[128 * 32];
    __shared__ u16 Bs[128 * 32];
    const int tid = threadIdx.x;
    const int lane = tid & 63, w = tid >> 6;
    const int m0 = blockIdx.y * 128, n0 = blockIdx.x * 128;
    const int wm = w >> 1, wn = w & 1;
    f32x4 acc[4][4] = {};

    const int srow = 32 * w + (lane >> 2);
    const int scol = (lane & 3) * 8;

    for (int k0 = 0; k0 < K; k0 += 32) {
        gl_lds16(&A[(size_t)(m0 + srow) * K + k0 + scol], &As[w * 1024 + lane * 8]);
        gl_lds16(&A[(size_t)(m0 + srow + 16) * K + k0 + scol], &As[w * 1024 + 512 + lane * 8]);
        gl_lds16(&Bt[(size_t)(n0 + srow) * K + k0 + scol], &Bs[w * 1024 + lane * 8]);
        gl_lds16(&Bt[(size_t)(n0 + srow + 16) * K + k0 + scol], &Bs[w * 1024 + 512 + lane * 8]);
        __syncthreads();

        s16x8 af[4], bf[4];
#pragma unroll
        for (int mt = 0; mt < 4; mt++)
            af[mt] = *(const s16x8*)&As[(wm * 64 + mt * 16 + (lane & 15)) * 32 + (lane >> 4) * 8];
#pragma unroll
        for (int nt = 0; nt < 4; nt++)
            bf[nt] = *(const s16x8*)&Bs[(wn * 64 + nt * 16 + (lane & 15)) * 32 + (lane >> 4) * 8];
#pragma unroll
        for (int mt = 0; mt < 4; mt++)
#pragma unroll
            for (int nt = 0; nt < 4; nt++)
                acc[mt][nt] = __builtin_amdgcn_mfma_f32_16x16x32_bf16(af[mt], bf[nt], acc[mt][nt], 0, 0, 0);
        __syncthreads();
    }

#pragma unroll
    for (int mt = 0; mt < 4; mt++) {
        int row = m0 + wm * 64 + mt * 16 + (lane >> 4) * 4;
#pragma unroll
        for (int nt = 0; nt < 4; nt++) {
            int col = n0 + wn * 64 + nt * 16 + (lane & 15);
            float bs = bias[col];
#pragma unroll
            for (int r = 0; r < 4; r++) {
                float v = acc[mt][nt][r] + bs;
                if (OUT_BF16)
                    ((u16*)Cout)[(size_t)(row + r) * N + col] = f2b(v);
                else
                    ((float*)Cout)[(size_t)(row + r) * N + col] = v;
            }
        }
    }
}

// --------- V transpose: qkv v-part [b][t][h*64+d] -> Vt[b*16+h][d][t] ----
__global__ __launch_bounds__(256) void v_transpose(const u16* __restrict__ qkv,
                                                   u16* __restrict__ Vt) {
    __shared__ __align__(16) u16 s[64][72];
    const int t0 = blockIdx.x * 64;
    const int b = blockIdx.y >> 4, h = blockIdx.y & 15;
    const int t = threadIdx.x;
    const int r = t >> 2, c0 = (t & 3) * 16;
    const u16* src = qkv + (size_t)b * NT * (3 * NC) + (size_t)(t0 + r) * (3 * NC) + 2 * NC + h * HD + c0;
    *(s16x8*)&s[r][c0] = *(const s16x8*)src;
    *(s16x8*)&s[r][c0 + 8] = *(const s16x8*)(src + 8);
    __syncthreads();
    u32 arr[8];
#pragma unroll
    for (int jj = 0; jj < 8; jj++)
        arr[jj] = (u32)s[c0 + 2 * jj][r] | ((u32)s[c0 + 2 * jj + 1][r] << 16);
    u16* dst = Vt + ((size_t)(b * NH + h) * HD + r) * NT + t0 + c0;
    u32x4 lo, hi;
    lo[0] = arr[0]; lo[1] = arr[1]; lo[2] = arr[2]; lo[3] = arr[3];
    hi[0] = arr[4]; hi[1] = arr[5]; hi[2] = arr[6]; hi[3] = arr[7];
    *(u32x4*)dst = lo;
    *(u32x4*)(dst + 8) = hi;
}

// -------- causal flash attention: 4 indep waves/block, prefetch ----------
// global wave gw: qc = 63-(gw>>5) (longest first, uniform within block),
// head = gw&31. Blocks b, b+8, ... land on same XCD -> same 4 heads' K/V
// stay in that XCD's L2 (2 MB working set < 4 MB).
__global__ __launch_bounds__(256) void attn_kernel(const u16* __restrict__ qkv,
                                                   const u16* __restrict__ Vt,
                                                   u16* __restrict__ yb) {
    const int l = threadIdx.x & 63;
    const int q16 = l & 15, g = l >> 4;
    const int gw = blockIdx.x * 4 + (threadIdx.x >> 6);
    const int qc = 63 - (gw >> 5);
    const int hh = gw & 31;
    const int b = hh >> 4, h = hh & 15;
    const int qw = qc * 32;

    const u16* qkvb = qkv + (size_t)b * NT * (3 * NC);
    s16x8 qf[2][2];
#pragma unroll
    for (int j = 0; j < 2; j++)
#pragma unroll
        for (int kc = 0; kc < 2; kc++)
            qf[j][kc] = *(const s16x8*)(qkvb + (size_t)(qw + 16 * j + q16) * (3 * NC) + h * HD + kc * 32 + g * 8);

    const u16* kb = qkvb + (size_t)q16 * (3 * NC) + NC + h * HD + g * 8;
    const u16* vtb = Vt + ((size_t)(b * NH + h) * HD + q16) * NT + g * 8;

    f32x4 yacc[4][2] = {};  // [dt][j]: y^T, row d=16dt+4g+r, col q=q16 (+16j)
    float m2[2] = {-INFINITY, -INFINITY};
    float lsum[2] = {0.f, 0.f};
    const float sc2 = 0.125f * 1.44269504088896340736f;  // scale * log2(e)

    auto loadt = [&](int kv0, s16x8 (&kf)[2][2], s16x8 (&vf)[4]) {
#pragma unroll
        for (int i = 0; i < 2; i++)
#pragma unroll
            for (int kc = 0; kc < 2; kc++)
                kf[i][kc] = *(const s16x8*)(kb + (size_t)(kv0 + 16 * i) * (3 * NC) + kc * 32);
#pragma unroll
        for (int dt = 0; dt < 4; dt++)
            vf[dt] = *(const s16x8*)(vtb + (size_t)(16 * dt) * NT + kv0);
    };

    auto compute = [&](int kv0, const s16x8 (&kf)[2][2], const s16x8 (&vf)[4]) {
        // S^T = K Q^T : lane holds S[q=16j+q16][kv=kv0+16i+4g+r]
        f32x4 sacc[2][2] = {};
#pragma unroll
        for (int i = 0; i < 2; i++)
#pragma unroll
            for (int kc = 0; kc < 2; kc++)
#pragma unroll
                for (int j = 0; j < 2; j++)
                    sacc[i][j] = __builtin_amdgcn_mfma_f32_16x16x32_bf16(kf[i][kc], qf[j][kc], sacc[i][j], 0, 0, 0);

        if (kv0 == qw) {  // diagonal tile: causal mask
#pragma unroll
            for (int i = 0; i < 2; i++)
#pragma unroll
                for (int j = 0; j < 2; j++)
#pragma unroll
                    for (int r = 0; r < 4; r++)
                        if (16 * i + 4 * g + r > 16 * j + q16) sacc[i][j][r] = -1e30f;
        }

        float pm[2];
#pragma unroll
        for (int j = 0; j < 2; j++) {
            float a = fmaxf(fmaxf(sacc[0][j][0], sacc[0][j][1]), fmaxf(sacc[0][j][2], sacc[0][j][3]));
            float c = fmaxf(fmaxf(sacc[1][j][0], sacc[1][j][1]), fmaxf(sacc[1][j][2], sacc[1][j][3]));
            pm[j] = fmaxf(a, c);
            pm[j] = fmaxf(pm[j], __shfl_xor(pm[j], 16));
            pm[j] = fmaxf(pm[j], __shfl_xor(pm[j], 32));
        }
        float need = fmaxf(pm[0] * sc2 - m2[0], pm[1] * sc2 - m2[1]);
        if (__any(need > 0.f)) {
#pragma unroll
            for (int j = 0; j < 2; j++) {
                float mn = fmaxf(m2[j], pm[j] * sc2);
                float al = exp2f(m2[j] - mn);
                m2[j] = mn;
                lsum[j] *= al;
#pragma unroll
                for (int dt = 0; dt < 4; dt++)
#pragma unroll
                    for (int r = 0; r < 4; r++) yacc[dt][j][r] *= al;
            }
        }

        float p[2][2][4], ps[2];
#pragma unroll
        for (int j = 0; j < 2; j++) {
            float s0 = 0.f;
#pragma unroll
            for (int i = 0; i < 2; i++)
#pragma unroll
                for (int r = 0; r < 4; r++) {
                    p[i][j][r] = exp2f(fmaf(sacc[i][j][r], sc2, -m2[j]));
                    s0 += p[i][j][r];
                }
            ps[j] = s0;
            ps[j] += __shfl_xor(ps[j], 16);
            ps[j] += __shfl_xor(ps[j], 32);
            lsum[j] += ps[j];
        }

        s16x8 pfrag[2];
#pragma unroll
        for (int j = 0; j < 2; j++) {
            u32 C0 = cvtpk(p[0][j][0], p[0][j][1]);
            u32 C1 = cvtpk(p[0][j][2], p[0][j][3]);
            u32 D0 = cvtpk(p[1][j][0], p[1][j][1]);
            u32 D1 = cvtpk(p[1][j][2], p[1][j][3]);
            swap32(C0, D0); swap16(C0, D0);
            swap32(C1, D1); swap16(C1, D1);
            u32x4 fr;
            fr[0] = C0; fr[1] = C1; fr[2] = D0; fr[3] = D1;
            pfrag[j] = __builtin_bit_cast(s16x8, fr);
        }

#pragma unroll
        for (int dt = 0; dt < 4; dt++)
#pragma unroll
            for (int j = 0; j < 2; j++)
                yacc[dt][j] = __builtin_amdgcn_mfma_f32_16x16x32_bf16(vf[dt], pfrag[j], yacc[dt][j], 0, 0, 0);
    };

    // 2-deep ping-pong pipeline over kv tiles
    const int ntiles = qc + 1;
    s16x8 kA[2][2], vA[4], kB[2][2], vB[4];
    loadt(0, kA, vA);
    int t = 0;
    for (; t + 2 <= ntiles; t += 2) {
        loadt((t + 1) * 32, kB, vB);
        compute(t * 32, kA, vA);
        if (t + 2 < ntiles) loadt((t + 2) * 32, kA, vA);
        compute((t + 1) * 32, kB, vB);
    }
    if (t < ntiles) compute(t * 32, kA, vA);

    // epilogue: yb[b][q][h*64+d] = y / l
#pragma unroll
    for (int j = 0; j < 2; j++) {
        float inv = 1.f / lsum[j];
        size_t rowoff = ((size_t)(b * NT + qw + 16 * j + q16)) * NC + h * HD;
#pragma unroll
        for (int dt = 0; dt < 4; dt++) {
            u32 lo = cvtpk(yacc[dt][j][0] * inv, yacc[dt][j][1] * inv);
            u32 hi = cvtpk(yacc[dt][j][2] * inv, yacc[dt][j][3] * inv);
            u64 pk = (u64)lo | ((u64)hi << 32);
            *(u64*)(yb + rowoff + 16 * dt + 4 * g) = pk;
        }
    }
}

extern "C" void kernel_launch(void* const* d_in, const int* in_sizes, int n_in,
                              void* d_out, int out_size, void* d_ws, size_t ws_size,
                              hipStream_t stream) {
    const float* x  = (const float*)d_in[0];
    const float* Wa = (const float*)d_in[2];
    const float* ba = (const float*)d_in[3];
    const float* Wp = (const float*)d_in[4];
    const float* bp = (const float*)d_in[5];
    float* out = (float*)d_out;

    char* ws = (char*)d_ws;
    u16* xb  = (u16*)(ws);                       // 8 MiB  [4096][1024]
    u16* WaT = (u16*)(ws + (8ull << 20));        // 6 MiB  [3072][1024]
    u16* WpT = (u16*)(ws + (14ull << 20));       // 2 MiB  [1024][1024]
    u16* qkv = (u16*)(ws + (16ull << 20));       // 24 MiB [4096][3072]
    u16* yb  = (u16*)(ws + (40ull << 20));       // 8 MiB  [4096][1024]
    u16* Vtb = (u16*)(ws + (48ull << 20));       // 8 MiB  [32][64][2048]

    const int M = NB * NT;  // 4096

    conv_bf16<<<(M * NC / 4 + 255) / 256, 256, 0, stream>>>(x, xb, M * NC / 4);
    transpose_bf16<<<dim3(3 * NC / 64, NC / 64), 256, 0, stream>>>(Wa, WaT, NC, 3 * NC);
    transpose_bf16<<<dim3(NC / 64, NC / 64), 256, 0, stream>>>(Wp, WpT, NC, NC);

    gemm_bt<1><<<dim3(3 * NC / 128, M / 128), 256, 0, stream>>>(xb, WaT, ba, qkv, M, 3 * NC, NC);

    v_transpose<<<dim3(NT / 64, NB * NH), 256, 0, stream>>>(qkv, Vtb);

    attn_kernel<<<dim3(NB * NH * 64 / 4), 256, 0, stream>>>(qkv, Vtb, yb);

    gemm_bt<0><<<dim3(NC / 128, M / 128), 256, 0, stream>>>(yb, WpT, bp, out, M, NC, NC);
}